// Round 6
// baseline (232.787 us; speedup 1.0000x reference)
//
#include <hip/hip_runtime.h>
#include <hip/hip_bf16.h>
#include <math.h>

#define B_ 2
#define N_ 6
#define C_ 80
#define FH_ 16
#define FW_ 44
#define D_ 112
#define NX_ 128
#define NY_ 128
#define HW_ (FH_ * FW_)             /* 704 */
#define NCOL (B_ * N_ * HW_)        /* 8448 */
#define NCELL (B_ * NY_ * NX_)      /* 32768 */
#define MAXT (NCOL * D_)            /* 946176 tuple capacity */
#define GB_CELLS 16                 /* cells per gather block (1 wave each) */
#define NCB 2112                    /* count blocks: 4 column-waves each -> 8448 cols */
#define NTB 2640                    /* transpose blocks: 1 elem/thread, NCOL*C/256 */

typedef __hip_bfloat16 bf16;
typedef unsigned short u16;

__device__ __forceinline__ float loadf(const void* p, int i, int isbf) {
  if (isbf) return __bfloat162float(((const bf16*)p)[i]);
  return ((const float*)p)[i];
}

// ---------- adjugate 4x4 inverse: static indexing only (no scratch!) ----------
__device__ void inv4(const float m[16], float invOut[16]) {
  float inv[16];
  inv[0]  =  m[5]*m[10]*m[15] - m[5]*m[11]*m[14] - m[9]*m[6]*m[15] + m[9]*m[7]*m[14] + m[13]*m[6]*m[11] - m[13]*m[7]*m[10];
  inv[4]  = -m[4]*m[10]*m[15] + m[4]*m[11]*m[14] + m[8]*m[6]*m[15] - m[8]*m[7]*m[14] - m[12]*m[6]*m[11] + m[12]*m[7]*m[10];
  inv[8]  =  m[4]*m[9]*m[15]  - m[4]*m[11]*m[13] - m[8]*m[5]*m[15] + m[8]*m[7]*m[13] + m[12]*m[5]*m[11] - m[12]*m[7]*m[9];
  inv[12] = -m[4]*m[9]*m[14]  + m[4]*m[10]*m[13] + m[8]*m[5]*m[14] - m[8]*m[6]*m[13] - m[12]*m[5]*m[10] + m[12]*m[6]*m[9];
  inv[1]  = -m[1]*m[10]*m[15] + m[1]*m[11]*m[14] + m[9]*m[2]*m[15] - m[9]*m[3]*m[14] - m[13]*m[2]*m[11] + m[13]*m[3]*m[10];
  inv[5]  =  m[0]*m[10]*m[15] - m[0]*m[11]*m[14] - m[8]*m[2]*m[15] + m[8]*m[3]*m[14] + m[12]*m[2]*m[11] - m[12]*m[3]*m[10];
  inv[9]  = -m[0]*m[9]*m[15]  + m[0]*m[11]*m[13] + m[8]*m[1]*m[15] - m[8]*m[3]*m[13] - m[12]*m[1]*m[11] + m[12]*m[3]*m[9];
  inv[13] =  m[0]*m[9]*m[14]  - m[0]*m[10]*m[13] - m[8]*m[1]*m[14] + m[8]*m[2]*m[13] + m[12]*m[1]*m[10] - m[12]*m[2]*m[9];
  inv[2]  =  m[1]*m[6]*m[15]  - m[1]*m[7]*m[14]  - m[5]*m[2]*m[15] + m[5]*m[3]*m[14] + m[13]*m[2]*m[7]  - m[13]*m[3]*m[6];
  inv[6]  = -m[0]*m[6]*m[15]  + m[0]*m[7]*m[14]  + m[4]*m[2]*m[15] - m[4]*m[3]*m[14] - m[12]*m[2]*m[7]  + m[12]*m[3]*m[6];
  inv[10] =  m[0]*m[5]*m[15]  - m[0]*m[7]*m[13]  - m[4]*m[1]*m[15] + m[4]*m[3]*m[13] + m[12]*m[1]*m[7]  - m[12]*m[3]*m[5];
  inv[14] = -m[0]*m[5]*m[14]  + m[0]*m[6]*m[13]  + m[4]*m[1]*m[14] - m[4]*m[2]*m[13] - m[12]*m[1]*m[6]  + m[12]*m[2]*m[5];
  inv[3]  = -m[1]*m[6]*m[11]  + m[1]*m[7]*m[10]  + m[5]*m[2]*m[11] - m[5]*m[3]*m[10] - m[9]*m[2]*m[7]   + m[9]*m[3]*m[6];
  inv[7]  =  m[0]*m[6]*m[11]  - m[0]*m[7]*m[10]  - m[4]*m[2]*m[11] + m[4]*m[3]*m[10] + m[8]*m[2]*m[7]   - m[8]*m[3]*m[6];
  inv[11] = -m[0]*m[5]*m[11]  + m[0]*m[7]*m[9]   + m[4]*m[1]*m[11] - m[4]*m[3]*m[9]  - m[8]*m[1]*m[7]   + m[8]*m[3]*m[5];
  inv[15] =  m[0]*m[5]*m[10]  - m[0]*m[6]*m[9]   - m[4]*m[1]*m[10] + m[4]*m[2]*m[9]  + m[8]*m[1]*m[6]   - m[8]*m[2]*m[5];
  float det = m[0]*inv[0] + m[1]*inv[4] + m[2]*inv[8] + m[3]*inv[12];
  det = 1.0f / det;
  for (int i = 0; i < 16; i++) invOut[i] = inv[i] * det;
}

__device__ void mul4(const float A[16], const float Bm[16], float Cm[16]) {
  for (int i = 0; i < 4; i++)
    for (int j = 0; j < 4; j++) {
      float s = 0.f;
      for (int k = 0; k < 4; k++) s += A[i * 4 + k] * Bm[k * 4 + j];
      Cm[i * 4 + j] = s;
    }
}

// ---------- shared geometry (VERBATIM, verified) ----------
__device__ __forceinline__ int geom_cell(const float* __restrict__ mats,
                                         int bn, int h, int w, int d) {
  const float* Ai = mats + bn * 32;
  const float* M = mats + bn * 32 + 16;
  float u = (float)w * (703.0f / 43.0f);
  float v = (float)h * 17.0f;
  float dep = 2.25f + 0.5f * (float)d;
  float p0 = ((Ai[0] * u + Ai[1] * v) + Ai[2] * dep) + Ai[3];
  float p1 = ((Ai[4] * u + Ai[5] * v) + Ai[6] * dep) + Ai[7];
  float p2 = ((Ai[8] * u + Ai[9] * v) + Ai[10] * dep) + Ai[11];
  float p3 = ((Ai[12] * u + Ai[13] * v) + Ai[14] * dep) + Ai[15];
  float q0 = p0 * p2, q1 = p1 * p2;
  float gx = ((M[0] * q0 + M[1] * q1) + M[2] * p2) + M[3] * p3;
  float gy = ((M[4] * q0 + M[5] * q1) + M[6] * p2) + M[7] * p3;
  float gz = ((M[8] * q0 + M[9] * q1) + M[10] * p2) + M[11] * p3;
  int ix = (int)floorf((gx + 51.2f) / 0.8f);
  int iy = (int)floorf((gy + 51.2f) / 0.8f);
  int iz = (int)floorf((gz + 5.0f) / 8.0f);
  bool valid = (ix >= 0) && (ix < NX_) && (iy >= 0) && (iy < NY_) && (iz == 0);
  int b = bn / N_;
  return valid ? (b * (NY_ * NX_) + iy * NX_ + ix) : -1;
}

// ---------- helper: fold matrices for all 12 (b,n) into dst (threads 0..11) --
__device__ __forceinline__ void build_mats(
    const void* s2e, const void* intrin, const void* ida, const void* bda,
    int mbf, int t, float* dst) {
  if (t < B_ * N_) {
    int b = t / N_;
    float S[16], I[16], A[16], Bd[16], Iinv[16], Ainv[16], Cm[16], M[16];
    for (int i = 0; i < 16; i++) {
      S[i]  = loadf(s2e,    t * 16 + i, mbf);
      I[i]  = loadf(intrin, t * 16 + i, mbf);
      A[i]  = loadf(ida,    t * 16 + i, mbf);
      Bd[i] = loadf(bda,    b * 16 + i, mbf);
    }
    inv4(I, Iinv);
    inv4(A, Ainv);
    mul4(S, Iinv, Cm);
    mul4(Bd, Cm, M);
    for (int i = 0; i < 16; i++) { dst[t * 32 + i] = Ainv[i]; dst[t * 32 + 16 + i] = M[i]; }
  }
}

// ---------- node A: count (4 col-waves/block, local mats) + transpose
//            + block0 publishes flags/mats + last-count-block scan ----------
__global__ __launch_bounds__(256) void lss_count(
    const void* __restrict__ ctx, const void* __restrict__ logits,
    const void* __restrict__ s2e, const void* __restrict__ intrin,
    const void* __restrict__ ida, const void* __restrict__ bda,
    float* __restrict__ mats_g, int* __restrict__ flags_g,
    int* __restrict__ counts, int* __restrict__ offsets,
    int* __restrict__ cursors, int* __restrict__ done,
    float* __restrict__ ctx_t) {
  const int t = threadIdx.x;
  const int blk = blockIdx.x;
  const int ln = t & 63;
  const int wv = t >> 6;

  __shared__ int s_b[4];

  if (blk >= NCB) {
    // ---- transpose (r0-verified orientation): local dtype detect via ballot
    const unsigned short* u = (const unsigned short*)logits;
    unsigned short v = u[2 * t];
    int e = (v >> 7) & 0xFF;
    unsigned long long bm = __ballot(v == 0 || (e >= 110 && e <= 136));
    if (ln == 0) s_b[wv] = __popcll(bm);
    __syncthreads();
    const int tbf = (s_b[0] + s_b[1] + s_b[2] + s_b[3] > 170) ? 1 : 0;
    const int i = (blk - NCB) * 256 + t;     // NTB*256 == NCOL*C exactly
    int col = i / C_, c = i - col * C_;
    int bn = col / HW_, r = col - bn * HW_;
    int h = r / FW_, w2 = r - h * FW_;
    ctx_t[i] = loadf(ctx, ((bn * C_ + c) * FH_ + h) * FW_ + w2, tbf);
    return;
  }

  // ---- count block: fold mats locally (threads 0..11) ----
  __shared__ float s_mats[B_ * N_ * 32];
  const float iv0 = ((const float*)intrin)[0];
  const int mbf = (iv0 > 100.f && iv0 < 1.0e6f) ? 0 : 1;
  build_mats(s2e, intrin, ida, bda, mbf, t, s_mats);

  // block 0: tensor dtype detect + publish globals for fill/gather
  int pred = 0;
  if (blk == 0) {
    const unsigned short* u = (const unsigned short*)logits;
    unsigned short v = u[2 * t];
    int e = (v >> 7) & 0xFF;
    pred = (v == 0 || (e >= 110 && e <= 136)) ? 1 : 0;
  }
  unsigned long long bm = __ballot(pred);
  if (ln == 0) s_b[wv] = __popcll(bm);
  __syncthreads();                           // covers s_mats + s_b
  if (blk == 0) {
    if (t == 0) {
      flags_g[0] = (s_b[0] + s_b[1] + s_b[2] + s_b[3] > 170) ? 1 : 0;
      flags_g[1] = mbf;
    }
    if (t < B_ * N_)
      for (int i = 0; i < 32; i++) mats_g[t * 32 + i] = s_mats[t * 32 + i];
  }

  // ---- 4 column-waves: shuffle run-head count (verified r1/r4/r5 logic) ----
  {
    const int col = blk * 4 + wv;
    const int w = col % FW_;
    const int h = (col / FW_) % FH_;
    const int bn = col / (FW_ * FH_);
    int c0 = geom_cell(s_mats, bn, h, w, ln);
    int c1 = (ln < D_ - 64) ? geom_cell(s_mats, bn, h, w, ln + 64) : -3;
    int p0 = __shfl_up(c0, 1);          // cell(d-1) for d=ln
    int p1 = __shfl_up(c1, 1);          // cell(d-1) for d=ln+64 (ln>=1)
    int c63 = __shfl(c0, 63);           // cell(63) — predecessor of d=64
    if (ln == 0) p1 = c63;
    if (c0 >= 0 && (ln == 0 || p0 != c0)) atomicAdd(&counts[c0], 1);
    if (c1 >= 0 && p1 != c1) atomicAdd(&counts[c1], 1);
  }

  // ---- last count block performs the scan (r3/r4-verified pattern,
  //      MLP-fixed: 8 independent coherent loads per group, not a chain) ----
  __syncthreads();
  __shared__ int s_last;
  if (t == 0) {
    __threadfence();                         // release: counts atomics visible
    s_last = (atomicAdd(done, 1) == NCB - 1);
  }
  __syncthreads();
  if (!s_last) return;
  __threadfence();                           // acquire

  const int cb = t * 128;
#define LDC(k) __hip_atomic_load(&counts[cb + j + (k)], __ATOMIC_RELAXED, __HIP_MEMORY_SCOPE_AGENT)
  int tot = 0;
#pragma unroll 2
  for (int j = 0; j < 128; j += 8) {
    int a0 = LDC(0), a1 = LDC(1), a2 = LDC(2), a3 = LDC(3);
    int a4 = LDC(4), a5 = LDC(5), a6 = LDC(6), a7 = LDC(7);
    tot += ((a0 + a1) + (a2 + a3)) + ((a4 + a5) + (a6 + a7));
  }
  // exclusive prefix over the 256 per-thread chunk sums: wave shuffle scan
  int incl = tot;
#pragma unroll
  for (int s = 1; s < 64; s <<= 1) {
    int u2 = __shfl_up(incl, s);
    if (ln >= s) incl += u2;
  }
  __shared__ int s_wsum[4];
  if (ln == 63) s_wsum[wv] = incl;
  __syncthreads();
  int wbase = 0;
  for (int k = 0; k < wv; k++) wbase += s_wsum[k];
  int run = wbase + incl - tot;              // exclusive prefix for this chunk
#pragma unroll 2
  for (int j = 0; j < 128; j += 8) {
    int a0 = LDC(0), a1 = LDC(1), a2 = LDC(2), a3 = LDC(3);
    int a4 = LDC(4), a5 = LDC(5), a6 = LDC(6), a7 = LDC(7);
    offsets[cb + j + 0] = run; cursors[cb + j + 0] = run; run += a0;
    offsets[cb + j + 1] = run; cursors[cb + j + 1] = run; run += a1;
    offsets[cb + j + 2] = run; cursors[cb + j + 2] = run; run += a2;
    offsets[cb + j + 3] = run; cursors[cb + j + 3] = run; run += a3;
    offsets[cb + j + 4] = run; cursors[cb + j + 4] = run; run += a4;
    offsets[cb + j + 5] = run; cursors[cb + j + 5] = run; run += a5;
    offsets[cb + j + 6] = run; cursors[cb + j + 6] = run; run += a6;
    offsets[cb + j + 7] = run; cursors[cb + j + 7] = run; run += a7;
  }
#undef LDC
}

// ---------- node B: fill — 4 columns/block (verbatim per-wave logic) ----------
__global__ __launch_bounds__(256) void lss_fill(
    const void* __restrict__ logits, const float* __restrict__ mats,
    const int* __restrict__ flags, int* __restrict__ cursors,
    u16* __restrict__ colids, float* __restrict__ wts) {
  const int t = threadIdx.x;
  const int wv = t >> 6;
  const int tid = t & 63;
  const int col = blockIdx.x * 4 + wv;
  const int w = col % FW_;
  const int h = (col / FW_) % FH_;
  const int bn = col / (FW_ * FH_);
  const int tbf = flags[0];

  __shared__ float s_w[4][D_];
  __shared__ int s_cell[4][D_];

  const int base = ((bn * D_) * FH_ + h) * FW_ + w;
  float l0 = loadf(logits, base + tid * (FH_ * FW_), tbf);
  float l1 = (tid < D_ - 64) ? loadf(logits, base + (tid + 64) * (FH_ * FW_), tbf) : -1e30f;
  float m = fmaxf(l0, l1);
  for (int s = 32; s > 0; s >>= 1) m = fmaxf(m, __shfl_xor(m, s));
  float e0 = expf(l0 - m);
  float e1 = (tid < D_ - 64) ? expf(l1 - m) : 0.f;
  float sum = e0 + e1;
  for (int s = 32; s > 0; s >>= 1) sum += __shfl_xor(sum, s);
  float inv_sum = 1.0f / sum;

  s_w[wv][tid] = e0;
  s_cell[wv][tid] = geom_cell(mats, bn, h, w, tid);
  if (tid < D_ - 64) {
    s_w[wv][tid + 64] = e1;
    s_cell[wv][tid + 64] = geom_cell(mats, bn, h, w, tid + 64);
  }
  __syncthreads();

  for (int d = tid; d < D_; d += 64) {
    int vcell = s_cell[wv][d];
    if (vcell >= 0 && (d == 0 || s_cell[wv][d - 1] != vcell)) {
      float acc = s_w[wv][d];
      for (int j = d + 1; j < D_ && s_cell[wv][j] == vcell; ++j) acc += s_w[wv][j];
      int pos = atomicAdd(&cursors[vcell], 1);
      colids[pos] = (u16)col;
      wts[pos] = acc * inv_sum;
    }
  }
}

// ---------- node C: gather (verbatim, verified) ----------
__global__ __launch_bounds__(1024) void lss_gather(
    const float* __restrict__ ctx_t, const int* __restrict__ counts,
    const int* __restrict__ offsets, const u16* __restrict__ colids,
    const float* __restrict__ wts, const int* __restrict__ flags,
    void* __restrict__ out) {
  __shared__ float s_out[GB_CELLS * 84];
  const int tid = threadIdx.x;
  const int wv = tid >> 6;          // local cell 0..15
  const int ln = tid & 63;
  const int sl = ln >> 2;           // j-slice 0..15
  const int g = ln & 3;             // channel quarter
  const int cell = blockIdx.x * GB_CELLS + wv;
  const int n = counts[cell];
  const int off = offsets[cell];

  float acc[20];
#pragma unroll
  for (int i = 0; i < 20; i++) acc[i] = 0.f;

  for (int j = sl; j < n; j += 16) {
    int colj = colids[off + j];
    float wj = wts[off + j];
    const float4* cp = (const float4*)(ctx_t + colj * C_ + g * 20);
#pragma unroll
    for (int q = 0; q < 5; q++) {
      float4 v = cp[q];
      acc[q * 4 + 0] += wj * v.x;
      acc[q * 4 + 1] += wj * v.y;
      acc[q * 4 + 2] += wj * v.z;
      acc[q * 4 + 3] += wj * v.w;
    }
  }
#pragma unroll
  for (int msk = 4; msk <= 32; msk <<= 1) {
#pragma unroll
    for (int i = 0; i < 20; i++) acc[i] += __shfl_xor(acc[i], msk);
  }
  if (sl == 0) {
#pragma unroll
    for (int i = 0; i < 20; i++) s_out[wv * 84 + g * 20 + i] = acc[i];
  }
  __syncthreads();

  const int x = tid & 15;
  const int c0 = tid >> 4;          // 0..63
  const int cell0 = blockIdx.x * GB_CELLS;
  const int b = cell0 >> 14;
  const int yx0 = cell0 & 16383;
  if (flags[0]) {
    bf16* o = (bf16*)out;
    o[(size_t)(b * C_ + c0) * (NY_ * NX_) + yx0 + x] = __float2bfloat16(s_out[x * 84 + c0]);
    if (c0 < 16)
      o[(size_t)(b * C_ + 64 + c0) * (NY_ * NX_) + yx0 + x] = __float2bfloat16(s_out[x * 84 + 64 + c0]);
  } else {
    float* o = (float*)out;
    o[(size_t)(b * C_ + c0) * (NY_ * NX_) + yx0 + x] = s_out[x * 84 + c0];
    if (c0 < 16)
      o[(size_t)(b * C_ + 64 + c0) * (NY_ * NX_) + yx0 + x] = s_out[x * 84 + 64 + c0];
  }
}

extern "C" void kernel_launch(void* const* d_in, const int* in_sizes, int n_in,
                              void* d_out, int out_size, void* d_ws, size_t ws_size,
                              hipStream_t stream) {
  const void* ctx = d_in[0];
  const void* logits = d_in[1];
  const void* s2e = d_in[2];
  const void* intrin = d_in[3];
  const void* ida = d_in[4];
  const void* bda = d_in[5];

  float* wsf = (float*)d_ws;
  int* flags   = (int*)wsf;                 // [0],[1] flags (written by count blk0)
  float* mats  = wsf + 16;                  // 384 floats (written by count blk0)
  int* counts  = (int*)(wsf + 512);         // NCELL
  int* done    = counts + NCELL;            // 1 (padded to 16), memset with counts
  int* offsets = counts + NCELL + 16;       // NCELL
  int* cursors = offsets + NCELL;           // NCELL
  float* ctx_t = (float*)(cursors + NCELL); // NCOL*C floats
  float* wts   = ctx_t + NCOL * C_;         // MAXT floats
  u16* colids  = (u16*)(wts + MAXT);        // MAXT u16
  (void)done;

  hipMemsetAsync(counts, 0, (NCELL + 16) * sizeof(int), stream);
  lss_count<<<NCB + NTB, 256, 0, stream>>>(ctx, logits, s2e, intrin, ida, bda,
                                           mats, flags, counts, offsets,
                                           cursors, counts + NCELL, ctx_t);
  lss_fill<<<NCOL / 4, 256, 0, stream>>>(logits, mats, flags, cursors, colids, wts);
  lss_gather<<<NCELL / GB_CELLS, 1024, 0, stream>>>(ctx_t, counts, offsets, colids, wts, flags, d_out);
}

// Round 7
// 175.530 us; speedup vs baseline: 1.3262x; 1.3262x over previous
//
#include <hip/hip_runtime.h>
#include <hip/hip_bf16.h>
#include <math.h>

#define B_ 2
#define N_ 6
#define C_ 80
#define FH_ 16
#define FW_ 44
#define D_ 112
#define NX_ 128
#define NY_ 128
#define HW_ (FH_ * FW_)             /* 704 */
#define NCOL (B_ * N_ * HW_)        /* 8448 */
#define NCELL (B_ * NY_ * NX_)      /* 32768 */
#define MAXT (NCOL * D_)            /* 946176 tuple capacity */
#define GB_CELLS 16                 /* cells per gather block (1 wave each) */
#define NCB 2112                    /* count blocks: 4 column-waves each -> 8448 cols */
#define NTB 2640                    /* transpose blocks: 1 elem/thread, NCOL*C/256 */

typedef __hip_bfloat16 bf16;
typedef unsigned short u16;

__device__ __forceinline__ float loadf(const void* p, int i, int isbf) {
  if (isbf) return __bfloat162float(((const bf16*)p)[i]);
  return ((const float*)p)[i];
}

// ---------- adjugate 4x4 inverse: static indexing only (no scratch!) ----------
__device__ void inv4(const float m[16], float invOut[16]) {
  float inv[16];
  inv[0]  =  m[5]*m[10]*m[15] - m[5]*m[11]*m[14] - m[9]*m[6]*m[15] + m[9]*m[7]*m[14] + m[13]*m[6]*m[11] - m[13]*m[7]*m[10];
  inv[4]  = -m[4]*m[10]*m[15] + m[4]*m[11]*m[14] + m[8]*m[6]*m[15] - m[8]*m[7]*m[14] - m[12]*m[6]*m[11] + m[12]*m[7]*m[10];
  inv[8]  =  m[4]*m[9]*m[15]  - m[4]*m[11]*m[13] - m[8]*m[5]*m[15] + m[8]*m[7]*m[13] + m[12]*m[5]*m[11] - m[12]*m[7]*m[9];
  inv[12] = -m[4]*m[9]*m[14]  + m[4]*m[10]*m[13] + m[8]*m[5]*m[14] - m[8]*m[6]*m[13] - m[12]*m[5]*m[10] + m[12]*m[6]*m[9];
  inv[1]  = -m[1]*m[10]*m[15] + m[1]*m[11]*m[14] + m[9]*m[2]*m[15] - m[9]*m[3]*m[14] - m[13]*m[2]*m[11] + m[13]*m[3]*m[10];
  inv[5]  =  m[0]*m[10]*m[15] - m[0]*m[11]*m[14] - m[8]*m[2]*m[15] + m[8]*m[3]*m[14] + m[12]*m[2]*m[11] - m[12]*m[3]*m[10];
  inv[9]  = -m[0]*m[9]*m[15]  + m[0]*m[11]*m[13] + m[8]*m[1]*m[15] - m[8]*m[3]*m[13] - m[12]*m[1]*m[11] + m[12]*m[3]*m[9];
  inv[13] =  m[0]*m[9]*m[14]  - m[0]*m[10]*m[13] - m[8]*m[1]*m[14] + m[8]*m[2]*m[13] + m[12]*m[1]*m[10] - m[12]*m[2]*m[9];
  inv[2]  =  m[1]*m[6]*m[15]  - m[1]*m[7]*m[14]  - m[5]*m[2]*m[15] + m[5]*m[3]*m[14] + m[13]*m[2]*m[7]  - m[13]*m[3]*m[6];
  inv[6]  = -m[0]*m[6]*m[15]  + m[0]*m[7]*m[14]  + m[4]*m[2]*m[15] - m[4]*m[3]*m[14] - m[12]*m[2]*m[7]  + m[12]*m[3]*m[6];
  inv[10] =  m[0]*m[5]*m[15]  - m[0]*m[7]*m[13]  - m[4]*m[1]*m[15] + m[4]*m[3]*m[13] + m[12]*m[1]*m[7]  - m[12]*m[3]*m[5];
  inv[14] = -m[0]*m[5]*m[14]  + m[0]*m[6]*m[13]  + m[4]*m[1]*m[14] - m[4]*m[2]*m[13] - m[12]*m[1]*m[6]  + m[12]*m[2]*m[5];
  inv[3]  = -m[1]*m[6]*m[11]  + m[1]*m[7]*m[10]  + m[5]*m[2]*m[11] - m[5]*m[3]*m[10] - m[9]*m[2]*m[7]   + m[9]*m[3]*m[6];
  inv[7]  =  m[0]*m[6]*m[11]  - m[0]*m[7]*m[10]  - m[4]*m[2]*m[11] + m[4]*m[3]*m[10] + m[8]*m[2]*m[7]   - m[8]*m[3]*m[6];
  inv[11] = -m[0]*m[5]*m[11]  + m[0]*m[7]*m[9]   + m[4]*m[1]*m[11] - m[4]*m[3]*m[9]  - m[8]*m[1]*m[7]   + m[8]*m[3]*m[5];
  inv[15] =  m[0]*m[5]*m[10]  - m[0]*m[6]*m[9]   - m[4]*m[1]*m[10] + m[4]*m[2]*m[9]  + m[8]*m[1]*m[6]   - m[8]*m[2]*m[5];
  float det = m[0]*inv[0] + m[1]*inv[4] + m[2]*inv[8] + m[3]*inv[12];
  det = 1.0f / det;
  for (int i = 0; i < 16; i++) invOut[i] = inv[i] * det;
}

__device__ void mul4(const float A[16], const float Bm[16], float Cm[16]) {
  for (int i = 0; i < 4; i++)
    for (int j = 0; j < 4; j++) {
      float s = 0.f;
      for (int k = 0; k < 4; k++) s += A[i * 4 + k] * Bm[k * 4 + j];
      Cm[i * 4 + j] = s;
    }
}

// ---------- shared geometry (VERBATIM, verified) ----------
__device__ __forceinline__ int geom_cell(const float* __restrict__ mats,
                                         int bn, int h, int w, int d) {
  const float* Ai = mats + bn * 32;
  const float* M = mats + bn * 32 + 16;
  float u = (float)w * (703.0f / 43.0f);
  float v = (float)h * 17.0f;
  float dep = 2.25f + 0.5f * (float)d;
  float p0 = ((Ai[0] * u + Ai[1] * v) + Ai[2] * dep) + Ai[3];
  float p1 = ((Ai[4] * u + Ai[5] * v) + Ai[6] * dep) + Ai[7];
  float p2 = ((Ai[8] * u + Ai[9] * v) + Ai[10] * dep) + Ai[11];
  float p3 = ((Ai[12] * u + Ai[13] * v) + Ai[14] * dep) + Ai[15];
  float q0 = p0 * p2, q1 = p1 * p2;
  float gx = ((M[0] * q0 + M[1] * q1) + M[2] * p2) + M[3] * p3;
  float gy = ((M[4] * q0 + M[5] * q1) + M[6] * p2) + M[7] * p3;
  float gz = ((M[8] * q0 + M[9] * q1) + M[10] * p2) + M[11] * p3;
  int ix = (int)floorf((gx + 51.2f) / 0.8f);
  int iy = (int)floorf((gy + 51.2f) / 0.8f);
  int iz = (int)floorf((gz + 5.0f) / 8.0f);
  bool valid = (ix >= 0) && (ix < NX_) && (iy >= 0) && (iy < NY_) && (iz == 0);
  int b = bn / N_;
  return valid ? (b * (NY_ * NX_) + iy * NX_ + ix) : -1;
}

// ---------- node 1: flags + mats (block 0) + distributed zero of counts ----
__global__ __launch_bounds__(256) void lss_prep(
    const void* __restrict__ logits,
    const void* __restrict__ s2e, const void* __restrict__ intrin,
    const void* __restrict__ ida, const void* __restrict__ bda,
    float* __restrict__ mats, int* __restrict__ flags,
    int* __restrict__ counts) {
  const int t = threadIdx.x;
  const int blk = blockIdx.x;
  for (int i = blk * 256 + t; i < NCELL; i += 33 * 256) counts[i] = 0;
  if (blk != 0) return;

  __shared__ int s_cnt;
  __shared__ int s_mats_bf;
  if (t == 0) s_cnt = 0;
  __syncthreads();
  {
    const unsigned short* u = (const unsigned short*)logits;
    unsigned short v = u[2 * t];
    int e = (v >> 7) & 0xFF;
    if (v == 0 || (e >= 110 && e <= 136)) atomicAdd(&s_cnt, 1);
  }
  __syncthreads();
  if (t == 0) {
    flags[0] = (s_cnt > 170) ? 1 : 0;  // tensors bf16?
    float v = ((const float*)intrin)[0];
    s_mats_bf = (v > 100.f && v < 1.0e6f) ? 0 : 1;
    flags[1] = s_mats_bf;
  }
  __syncthreads();
  const int mbf = s_mats_bf;
  if (t < B_ * N_) {
    int b = t / N_;
    float S[16], I[16], A[16], Bd[16], Iinv[16], Ainv[16], Cm[16], M[16];
    for (int i = 0; i < 16; i++) {
      S[i]  = loadf(s2e,    t * 16 + i, mbf);
      I[i]  = loadf(intrin, t * 16 + i, mbf);
      A[i]  = loadf(ida,    t * 16 + i, mbf);
      Bd[i] = loadf(bda,    b * 16 + i, mbf);
    }
    inv4(I, Iinv);
    inv4(A, Ainv);
    mul4(S, Iinv, Cm);
    mul4(Bd, Cm, M);
    for (int i = 0; i < 16; i++) { mats[t * 32 + i] = Ainv[i]; mats[t * 32 + 16 + i] = M[i]; }
  }
}

// ---------- node 2: count (4 column-waves/block) + transpose (r0 orientation)
__global__ __launch_bounds__(256) void lss_count(
    const void* __restrict__ ctx, const float* __restrict__ mats,
    const int* __restrict__ flags, int* __restrict__ counts,
    float* __restrict__ ctx_t) {
  const int t = threadIdx.x;
  const int blk = blockIdx.x;

  if (blk >= NCB) {
    // ---- transpose, round-0 verified orientation: strided read, linear write
    const int tbf = flags[0];
    const int i = (blk - NCB) * 256 + t;     // NTB*256 == NCOL*C exactly
    int col = i / C_, c = i - col * C_;
    int bn = col / HW_, r = col - bn * HW_;
    int h = r / FW_, w = r - h * FW_;
    ctx_t[i] = loadf(ctx, ((bn * C_ + c) * FH_ + h) * FW_ + w, tbf);
    return;
  }

  // ---- 4 column-waves per block (shuffle run-head count, verified) ----
  const int col = blk * 4 + (t >> 6);
  const int ln = t & 63;
  const int w = col % FW_;
  const int h = (col / FW_) % FH_;
  const int bn = col / (FW_ * FH_);
  int c0 = geom_cell(mats, bn, h, w, ln);
  int c1 = (ln < D_ - 64) ? geom_cell(mats, bn, h, w, ln + 64) : -3;
  int p0 = __shfl_up(c0, 1);          // cell(d-1) for d=ln
  int p1 = __shfl_up(c1, 1);          // cell(d-1) for d=ln+64 (ln>=1)
  int c63 = __shfl(c0, 63);           // cell(63) — predecessor of d=64
  if (ln == 0) p1 = c63;
  if (c0 >= 0 && (ln == 0 || p0 != c0)) atomicAdd(&counts[c0], 1);
  if (c1 >= 0 && p1 != c1) atomicAdd(&counts[c1], 1);
}

// ---------- node 3: scan — plain int4 loads, wave shuffle scan (2 barriers) --
__global__ __launch_bounds__(1024) void lss_scan(const int* __restrict__ counts,
                                                 int* __restrict__ offsets,
                                                 int* __restrict__ cursors) {
  const int t = threadIdx.x;
  const int ln = t & 63;
  const int wv = t >> 6;                     // 16 waves
  const int base = t * 32;

  int4 v[8];
  const int4* cp = (const int4*)(counts + base);
#pragma unroll
  for (int j = 0; j < 8; j++) v[j] = cp[j];
  int tsum = 0;
#pragma unroll
  for (int j = 0; j < 8; j++) tsum += (v[j].x + v[j].y) + (v[j].z + v[j].w);

  // 64-lane inclusive shuffle scan of per-thread sums
  int incl = tsum;
#pragma unroll
  for (int s = 1; s < 64; s <<= 1) {
    int u = __shfl_up(incl, s);
    if (ln >= s) incl += u;
  }
  __shared__ int s_wtot[16];
  if (ln == 63) s_wtot[wv] = incl;
  __syncthreads();
  int wbase = 0;
  for (int k = 0; k < wv; k++) wbase += s_wtot[k];
  int run = wbase + incl - tsum;             // exclusive prefix for this thread

#pragma unroll
  for (int j = 0; j < 8; j++) {
    int4 o;
    o.x = run; run += v[j].x;
    o.y = run; run += v[j].y;
    o.z = run; run += v[j].z;
    o.w = run; run += v[j].w;
    ((int4*)(offsets + base))[j] = o;
    ((int4*)(cursors + base))[j] = o;
  }
}

// ---------- node 4: fill — 4 columns/block (r6-verified batching) ----------
__global__ __launch_bounds__(256) void lss_fill(
    const void* __restrict__ logits, const float* __restrict__ mats,
    const int* __restrict__ flags, int* __restrict__ cursors,
    u16* __restrict__ colids, float* __restrict__ wts) {
  const int t = threadIdx.x;
  const int wv = t >> 6;
  const int tid = t & 63;
  const int col = blockIdx.x * 4 + wv;
  const int w = col % FW_;
  const int h = (col / FW_) % FH_;
  const int bn = col / (FW_ * FH_);
  const int tbf = flags[0];

  __shared__ float s_w[4][D_];
  __shared__ int s_cell[4][D_];

  const int base = ((bn * D_) * FH_ + h) * FW_ + w;
  float l0 = loadf(logits, base + tid * (FH_ * FW_), tbf);
  float l1 = (tid < D_ - 64) ? loadf(logits, base + (tid + 64) * (FH_ * FW_), tbf) : -1e30f;
  float m = fmaxf(l0, l1);
  for (int s = 32; s > 0; s >>= 1) m = fmaxf(m, __shfl_xor(m, s));
  float e0 = expf(l0 - m);
  float e1 = (tid < D_ - 64) ? expf(l1 - m) : 0.f;
  float sum = e0 + e1;
  for (int s = 32; s > 0; s >>= 1) sum += __shfl_xor(sum, s);
  float inv_sum = 1.0f / sum;

  s_w[wv][tid] = e0;
  s_cell[wv][tid] = geom_cell(mats, bn, h, w, tid);
  if (tid < D_ - 64) {
    s_w[wv][tid + 64] = e1;
    s_cell[wv][tid + 64] = geom_cell(mats, bn, h, w, tid + 64);
  }
  __syncthreads();

  for (int d = tid; d < D_; d += 64) {
    int vcell = s_cell[wv][d];
    if (vcell >= 0 && (d == 0 || s_cell[wv][d - 1] != vcell)) {
      float acc = s_w[wv][d];
      for (int j = d + 1; j < D_ && s_cell[wv][j] == vcell; ++j) acc += s_w[wv][j];
      int pos = atomicAdd(&cursors[vcell], 1);
      colids[pos] = (u16)col;
      wts[pos] = acc * inv_sum;
    }
  }
}

// ---------- node 5: gather (verbatim, verified) ----------
__global__ __launch_bounds__(1024) void lss_gather(
    const float* __restrict__ ctx_t, const int* __restrict__ counts,
    const int* __restrict__ offsets, const u16* __restrict__ colids,
    const float* __restrict__ wts, const int* __restrict__ flags,
    void* __restrict__ out) {
  __shared__ float s_out[GB_CELLS * 84];
  const int tid = threadIdx.x;
  const int wv = tid >> 6;          // local cell 0..15
  const int ln = tid & 63;
  const int sl = ln >> 2;           // j-slice 0..15
  const int g = ln & 3;             // channel quarter
  const int cell = blockIdx.x * GB_CELLS + wv;
  const int n = counts[cell];
  const int off = offsets[cell];

  float acc[20];
#pragma unroll
  for (int i = 0; i < 20; i++) acc[i] = 0.f;

  for (int j = sl; j < n; j += 16) {
    int colj = colids[off + j];
    float wj = wts[off + j];
    const float4* cp = (const float4*)(ctx_t + colj * C_ + g * 20);
#pragma unroll
    for (int q = 0; q < 5; q++) {
      float4 v = cp[q];
      acc[q * 4 + 0] += wj * v.x;
      acc[q * 4 + 1] += wj * v.y;
      acc[q * 4 + 2] += wj * v.z;
      acc[q * 4 + 3] += wj * v.w;
    }
  }
#pragma unroll
  for (int msk = 4; msk <= 32; msk <<= 1) {
#pragma unroll
    for (int i = 0; i < 20; i++) acc[i] += __shfl_xor(acc[i], msk);
  }
  if (sl == 0) {
#pragma unroll
    for (int i = 0; i < 20; i++) s_out[wv * 84 + g * 20 + i] = acc[i];
  }
  __syncthreads();

  const int x = tid & 15;
  const int c0 = tid >> 4;          // 0..63
  const int cell0 = blockIdx.x * GB_CELLS;
  const int b = cell0 >> 14;
  const int yx0 = cell0 & 16383;
  if (flags[0]) {
    bf16* o = (bf16*)out;
    o[(size_t)(b * C_ + c0) * (NY_ * NX_) + yx0 + x] = __float2bfloat16(s_out[x * 84 + c0]);
    if (c0 < 16)
      o[(size_t)(b * C_ + 64 + c0) * (NY_ * NX_) + yx0 + x] = __float2bfloat16(s_out[x * 84 + 64 + c0]);
  } else {
    float* o = (float*)out;
    o[(size_t)(b * C_ + c0) * (NY_ * NX_) + yx0 + x] = s_out[x * 84 + c0];
    if (c0 < 16)
      o[(size_t)(b * C_ + 64 + c0) * (NY_ * NX_) + yx0 + x] = s_out[x * 84 + 64 + c0];
  }
}

extern "C" void kernel_launch(void* const* d_in, const int* in_sizes, int n_in,
                              void* d_out, int out_size, void* d_ws, size_t ws_size,
                              hipStream_t stream) {
  const void* ctx = d_in[0];
  const void* logits = d_in[1];
  const void* s2e = d_in[2];
  const void* intrin = d_in[3];
  const void* ida = d_in[4];
  const void* bda = d_in[5];

  float* wsf = (float*)d_ws;
  int* flags   = (int*)wsf;                 // [0],[1] flags
  float* mats  = wsf + 16;                  // 384 floats used
  int* counts  = (int*)(wsf + 512);
  int* offsets = counts + NCELL;
  int* cursors = offsets + NCELL;
  float* ctx_t = (float*)(cursors + NCELL); // NCOL*C floats
  float* wts   = ctx_t + NCOL * C_;         // MAXT floats
  u16* colids  = (u16*)(wts + MAXT);        // MAXT u16

  lss_prep<<<33, 256, 0, stream>>>(logits, s2e, intrin, ida, bda, mats, flags, counts);
  lss_count<<<NCB + NTB, 256, 0, stream>>>(ctx, mats, flags, counts, ctx_t);
  lss_scan<<<1, 1024, 0, stream>>>(counts, offsets, cursors);
  lss_fill<<<NCOL / 4, 256, 0, stream>>>(logits, mats, flags, cursors, colids, wts);
  lss_gather<<<NCELL / GB_CELLS, 1024, 0, stream>>>(ctx_t, counts, offsets, colids, wts, flags, d_out);
}